// Round 3
// baseline (472.875 us; speedup 1.0000x reference)
//
#include <hip/hip_runtime.h>

// Problem constants (fixed by the reference setup_inputs)
#define T_ 4096
#define D_ 4096
#define O_ 4096
#define L_ 32
#define R_ 8

constexpr int BM = 128, BN = 128, BK = 64;

typedef __bf16 bf16x8 __attribute__((ext_vector_type(8)));
typedef float f32x4 __attribute__((ext_vector_type(4)));

// fp32 -> bf16 round-to-nearest-even
__device__ __forceinline__ unsigned short f2bf(float f) {
    unsigned int u = __float_as_uint(f);
    u = (u + 0x7fffu + ((u >> 16) & 1u)) >> 16;
    return (unsigned short)u;
}

// async global->LDS, 16B per lane. LDS dest = wave-uniform base + lane*16.
__device__ __forceinline__ void load_lds16(const void* g, void* l) {
    __builtin_amdgcn_global_load_lds((__attribute__((address_space(1))) void*)g,
                                     (__attribute__((address_space(3))) void*)l,
                                     16, 0, 0);
}

// ---------------------------------------------------------------------------
// Kernel 1: fp32 -> bf16 streaming conversion (one float4 / thread)
// ---------------------------------------------------------------------------
__global__ __launch_bounds__(256) void cvt_kernel(const float* __restrict__ src,
                                                  unsigned short* __restrict__ dst) {
    const int i = (blockIdx.x * 256 + threadIdx.x) * 4;
    float4 v = *(const float4*)&src[i];
    ushort4 o;
    o.x = f2bf(v.x); o.y = f2bf(v.y); o.z = f2bf(v.z); o.w = f2bf(v.w);
    *(ushort4*)&dst[i] = o;
}

// ---------------------------------------------------------------------------
// Kernel 2: shrink_full[t, l*8+r] = dot(x[t,:], A_all[l*8+r,:])  (bf16 MFMA)
// A_all = lora_a viewed as [256, D]. Tile 128x256, grid = T/128 = 32 blocks.
// 4 waves in 2x2; each wave 64 rows x 128 cols (4x8 MFMA tiles).
// Same XOR-swizzled LDS layout as gemm_lora.
// ---------------------------------------------------------------------------
__global__ __launch_bounds__(256) void shrink_gemm(const short* __restrict__ xb,
                                                   const short* __restrict__ ab,
                                                   float* __restrict__ sfull) {
    __shared__ short As[128 * BK];   // 16 KB
    __shared__ short Bs[256 * BK];   // 32 KB

    const int tid = threadIdx.x;
    const int lane = tid & 63;
    const int quad = lane >> 4;
    const int l15 = lane & 15;
    const int wave = tid >> 6;
    const int wm = wave >> 1;
    const int wn = wave & 1;
    const int t0 = blockIdx.x * 128;

    const int lr = lane >> 3;
    const int lc = (lane & 7) ^ lr;
    const short* agl = xb + (size_t)(t0 + wave * 8 + lr) * D_ + lc * 8;
    const short* bgl = ab + (size_t)(wave * 8 + lr) * D_ + lc * 8;
    short* asl = &As[wave * 512];
    short* bsl = &Bs[wave * 512];

    f32x4 acc[4][8];
#pragma unroll
    for (int mi = 0; mi < 4; ++mi)
#pragma unroll
        for (int ni = 0; ni < 8; ++ni)
            acc[mi][ni] = f32x4{0.f, 0.f, 0.f, 0.f};

    const int arow = wm * 64 + l15;
    const int brow = wn * 128 + l15;
    const int swz = l15 & 7;

    for (int k0 = 0; k0 < D_; k0 += BK) {
#pragma unroll
        for (int j = 0; j < 4; ++j)
            load_lds16(agl + (size_t)j * 32 * D_ + k0, asl + j * 2048);
#pragma unroll
        for (int j = 0; j < 8; ++j)
            load_lds16(bgl + (size_t)j * 32 * D_ + k0, bsl + j * 2048);
        __syncthreads();

#pragma unroll
        for (int kk = 0; kk < 2; ++kk) {
            const int cba = ((kk * 4 + quad) ^ swz) * 8;
            bf16x8 af[4], bfr[8];
#pragma unroll
            for (int i = 0; i < 4; ++i)
                af[i] = *(const bf16x8*)&As[(arow + i * 16) * BK + cba];
#pragma unroll
            for (int i = 0; i < 8; ++i)
                bfr[i] = *(const bf16x8*)&Bs[(brow + i * 16) * BK + cba];
#pragma unroll
            for (int mi = 0; mi < 4; ++mi)
#pragma unroll
                for (int ni = 0; ni < 8; ++ni)
                    acc[mi][ni] = __builtin_amdgcn_mfma_f32_16x16x32_bf16(
                        af[mi], bfr[ni], acc[mi][ni], 0, 0, 0);
        }
        __syncthreads();
    }

    // C/D layout: col = lane&15, row = quad*4 + reg
#pragma unroll
    for (int mi = 0; mi < 4; ++mi)
#pragma unroll
        for (int reg = 0; reg < 4; ++reg) {
            const int row = t0 + wm * 64 + mi * 16 + quad * 4 + reg;
#pragma unroll
            for (int ni = 0; ni < 8; ++ni) {
                const int col = wn * 128 + ni * 16 + l15;
                sfull[(size_t)row * 256 + col] = acc[mi][ni][reg];
            }
        }
}

// ---------------------------------------------------------------------------
// Kernel 3: bf16 MFMA GEMM, BK=64, XOR-swizzled LDS + fused LoRA epilogue.
// K-loop reordered: frags(kk0) -> MFMA(kk0) -> frags(kk1) -> barrier ->
// glds(k+1) -> MFMA(kk1), so the next tile's loads fly under the MFMA block
// instead of stalling at the vmcnt(0) drain immediately after issue.
// ---------------------------------------------------------------------------
__global__ __launch_bounds__(256) void gemm_lora(const short* __restrict__ xb,
                                                 const short* __restrict__ wb,
                                                 const float* __restrict__ base_bias,
                                                 const float* __restrict__ lora_b,
                                                 const float* __restrict__ bias_st,
                                                 const int* __restrict__ tli,
                                                 const float* __restrict__ sfull,
                                                 float* __restrict__ out) {
    __shared__ short As[BM * BK];   // 16 KB
    __shared__ short Bs[BN * BK];   // 16 KB

    const int tid = threadIdx.x;
    const int lane = tid & 63;
    const int quad = lane >> 4;
    const int l15 = lane & 15;
    const int wave = tid >> 6;
    const int wm = wave >> 1;
    const int wn = wave & 1;

    const int bn = blockIdx.x & 31;
    const int bm = blockIdx.x >> 5;
    const int t0 = bm * BM;
    const int o0 = bn * BN;

    const int lr = lane >> 3;
    const int lc = (lane & 7) ^ lr;
    const short* agl = xb + (size_t)(t0 + wave * 8 + lr) * D_ + lc * 8;
    const short* bgl = wb + (size_t)(o0 + wave * 8 + lr) * D_ + lc * 8;
    short* asl = &As[wave * 512];
    short* bsl = &Bs[wave * 512];

    f32x4 acc[4][4];
#pragma unroll
    for (int mi = 0; mi < 4; ++mi)
#pragma unroll
        for (int ni = 0; ni < 4; ++ni)
            acc[mi][ni] = f32x4{0.f, 0.f, 0.f, 0.f};

    const int arow = wm * 64 + l15;
    const int brow = wn * 64 + l15;
    const int swz = l15 & 7;

    // prologue: stage tile k=0
#pragma unroll
    for (int j = 0; j < 4; ++j) {
        load_lds16(agl, asl + j * 2048);
        load_lds16(bgl, bsl + j * 2048);
        agl += (size_t)32 * D_;   // rows advance with j; restore below
        bgl += (size_t)32 * D_;
    }
    agl -= (size_t)128 * D_;
    bgl -= (size_t)128 * D_;

    for (int k0 = 0; k0 < D_; k0 += BK) {
        __syncthreads();   // publish tile k0 (vmcnt drain)

        bf16x8 af0[4], bf0[4], af1[4], bf1[4];
        const int cb0 = (quad ^ swz) * 8;
        const int cb1 = ((4 + quad) ^ swz) * 8;
#pragma unroll
        for (int i = 0; i < 4; ++i) {
            af0[i] = *(const bf16x8*)&As[(arow + i * 16) * BK + cb0];
            bf0[i] = *(const bf16x8*)&Bs[(brow + i * 16) * BK + cb0];
        }
#pragma unroll
        for (int mi = 0; mi < 4; ++mi)
#pragma unroll
            for (int ni = 0; ni < 4; ++ni)
                acc[mi][ni] = __builtin_amdgcn_mfma_f32_16x16x32_bf16(
                    af0[mi], bf0[ni], acc[mi][ni], 0, 0, 0);
#pragma unroll
        for (int i = 0; i < 4; ++i) {
            af1[i] = *(const bf16x8*)&As[(arow + i * 16) * BK + cb1];
            bf1[i] = *(const bf16x8*)&Bs[(brow + i * 16) * BK + cb1];
        }
        __syncthreads();   // all waves done reading this tile

        if (k0 + BK < D_) {
            const int kn = k0 + BK;
#pragma unroll
            for (int j = 0; j < 4; ++j) {
                load_lds16(agl + (size_t)j * 32 * D_ + kn, asl + j * 2048);
                load_lds16(bgl + (size_t)j * 32 * D_ + kn, bsl + j * 2048);
            }
        }
#pragma unroll
        for (int mi = 0; mi < 4; ++mi)
#pragma unroll
            for (int ni = 0; ni < 4; ++ni)
                acc[mi][ni] = __builtin_amdgcn_mfma_f32_16x16x32_bf16(
                    af1[mi], bf1[ni], acc[mi][ni], 0, 0, 0);
    }

    // Epilogue: C/D layout col = lane&15, row = quad*4 + reg
    const int col_base = o0 + wn * 64 + l15;
#pragma unroll
    for (int mi = 0; mi < 4; ++mi) {
#pragma unroll
        for (int reg = 0; reg < 4; ++reg) {
            const int row = t0 + wm * 64 + mi * 16 + quad * 4 + reg;
            const int idx = tli[row];
            const bool valid = (idx >= 0);
            float4 s0 = {0.f, 0.f, 0.f, 0.f}, s1 = {0.f, 0.f, 0.f, 0.f};
            if (valid) {
                s0 = *(const float4*)&sfull[(size_t)row * 256 + idx * 8];
                s1 = *(const float4*)&sfull[(size_t)row * 256 + idx * 8 + 4];
            }
#pragma unroll
            for (int ni = 0; ni < 4; ++ni) {
                const int col = col_base + ni * 16;
                float r = acc[mi][ni][reg] + base_bias[col];
                if (valid) {
                    const float* bp = &lora_b[((size_t)idx * O_ + col) * R_];
                    float4 b0 = *(const float4*)&bp[0];
                    float4 b1 = *(const float4*)&bp[4];
                    r += bias_st[(size_t)idx * O_ + col];
                    r += s0.x * b0.x + s0.y * b0.y + s0.z * b0.z + s0.w * b0.w +
                         s1.x * b1.x + s1.y * b1.y + s1.z * b1.z + s1.w * b1.w;
                }
                out[(size_t)row * O_ + col] = r;
            }
        }
    }
}

// ---------------------------------------------------------------------------
extern "C" void kernel_launch(void* const* d_in, const int* in_sizes, int n_in,
                              void* d_out, int out_size, void* d_ws, size_t ws_size,
                              hipStream_t stream) {
    const float* x    = (const float*)d_in[0];   // [T,D]
    const float* w    = (const float*)d_in[1];   // [O,D]
    const float* bb   = (const float*)d_in[2];   // [O]
    const float* la   = (const float*)d_in[3];   // [L,1,R,D] == A_all [256,D]
    const float* lb   = (const float*)d_in[4];   // [L,1,O,R]
    const float* bs   = (const float*)d_in[5];   // [L,1,O]
    const int*   tli  = (const int*)d_in[6];     // [T]
    float* out = (float*)d_out;

    // ws: xb (T*D bf16) | wb (O*D bf16) | ab (256*D bf16) | sfull (T*256 f32)
    unsigned short* xb = (unsigned short*)d_ws;
    unsigned short* wb = xb + (size_t)T_ * D_;
    unsigned short* ab = wb + (size_t)O_ * D_;
    float* sfull = (float*)(ab + (size_t)256 * D_);

    cvt_kernel<<<(T_ * (size_t)D_) / 1024, 256, 0, stream>>>(x, xb);
    cvt_kernel<<<(256 * (size_t)D_) / 1024, 256, 0, stream>>>(la, ab);
    shrink_gemm<<<T_ / 128, 256, 0, stream>>>((const short*)xb, (const short*)ab, sfull);
    cvt_kernel<<<(O_ * (size_t)D_) / 1024, 256, 0, stream>>>(w, wb);
    gemm_lora<<<(T_ / BM) * (O_ / BN), 256, 0, stream>>>(
        (const short*)xb, (const short*)wb, bb, lb, bs, tli, sfull, out);
}

// Round 4
// 406.058 us; speedup vs baseline: 1.1646x; 1.1646x over previous
//
#include <hip/hip_runtime.h>

// Problem constants (fixed by the reference setup_inputs)
#define T_ 4096
#define D_ 4096
#define O_ 4096
#define L_ 32
#define R_ 8

constexpr int BM = 128, BN = 128, BK = 64;

typedef __bf16 bf16x8 __attribute__((ext_vector_type(8)));
typedef float f32x4 __attribute__((ext_vector_type(4)));

// fp32 -> bf16 round-to-nearest-even
__device__ __forceinline__ unsigned short f2bf(float f) {
    unsigned int u = __float_as_uint(f);
    u = (u + 0x7fffu + ((u >> 16) & 1u)) >> 16;
    return (unsigned short)u;
}

// async global->LDS, 16B per lane. LDS dest = wave-uniform base + lane*16.
__device__ __forceinline__ void load_lds16(const void* g, void* l) {
    __builtin_amdgcn_global_load_lds((__attribute__((address_space(1))) void*)g,
                                     (__attribute__((address_space(3))) void*)l,
                                     16, 0, 0);
}

// ---------------------------------------------------------------------------
// Kernel 1: fp32 -> bf16 streaming conversion (one float4 / thread)
// ---------------------------------------------------------------------------
__global__ __launch_bounds__(256) void cvt_kernel(const float* __restrict__ src,
                                                  unsigned short* __restrict__ dst) {
    const int i = (blockIdx.x * 256 + threadIdx.x) * 4;
    float4 v = *(const float4*)&src[i];
    ushort4 o;
    o.x = f2bf(v.x); o.y = f2bf(v.y); o.z = f2bf(v.z); o.w = f2bf(v.w);
    *(ushort4*)&dst[i] = o;
}

// ---------------------------------------------------------------------------
// Kernel 2: shrink_full[t, l*8+r] = dot(x[t,:], A_all[l*8+r,:])  (bf16 MFMA)
// A_all = lora_a viewed as [256, D]. Tile 16x256, grid = T/16 = 256 blocks
// (full-device occupancy; A_all is L2-resident so staging streams from L2).
// Each of 4 waves covers all 16 rows x 64 cols (1x4 MFMA tiles).
// XOR-swizzled LDS layout (row r, chunk cb stored at slot cb^(r&7)).
// ---------------------------------------------------------------------------
__global__ __launch_bounds__(256) void shrink_gemm(const short* __restrict__ xb,
                                                   const short* __restrict__ ab,
                                                   float* __restrict__ sfull) {
    __shared__ short As[16 * BK];    // 2 KB
    __shared__ short Bs[256 * BK];   // 32 KB

    const int tid = threadIdx.x;
    const int lane = tid & 63;
    const int quad = lane >> 4;
    const int l15 = lane & 15;
    const int wave = tid >> 6;
    const int t0 = blockIdx.x * 16;

    const int lr = lane >> 3;          // 0..7
    const int lc = (lane & 7) ^ lr;    // XOR-swizzled col-block (self-inverse)

    // B staging: wave w, issue j (0..7): rows w*64 + j*8 + lr
    const short* bgl = ab + (size_t)(wave * 64 + lr) * D_ + lc * 8;
    short* bsl = &Bs[wave * 4096];     // + j*512 shorts per issue
    // A staging (wave 0 only): issue j (0..1): rows j*8 + lr
    const short* agl = xb + (size_t)(t0 + lr) * D_ + lc * 8;

    f32x4 acc[4];
#pragma unroll
    for (int ni = 0; ni < 4; ++ni) acc[ni] = f32x4{0.f, 0.f, 0.f, 0.f};

    const int swz = l15 & 7;

    for (int k0 = 0; k0 < D_; k0 += BK) {
        if (wave == 0) {
#pragma unroll
            for (int j = 0; j < 2; ++j)
                load_lds16(agl + (size_t)j * 8 * D_ + k0, &As[j * 512]);
        }
#pragma unroll
        for (int j = 0; j < 8; ++j)
            load_lds16(bgl + (size_t)j * 8 * D_ + k0, bsl + j * 512);
        __syncthreads();

#pragma unroll
        for (int kk = 0; kk < 2; ++kk) {
            const int cba = ((kk * 4 + quad) ^ swz) * 8;
            bf16x8 af = *(const bf16x8*)&As[l15 * BK + cba];
            bf16x8 bfr[4];
#pragma unroll
            for (int i = 0; i < 4; ++i)
                bfr[i] = *(const bf16x8*)&Bs[(wave * 64 + i * 16 + l15) * BK + cba];
#pragma unroll
            for (int ni = 0; ni < 4; ++ni)
                acc[ni] = __builtin_amdgcn_mfma_f32_16x16x32_bf16(
                    af, bfr[ni], acc[ni], 0, 0, 0);
        }
        __syncthreads();
    }

    // C/D layout: col = lane&15, row = quad*4 + reg
#pragma unroll
    for (int ni = 0; ni < 4; ++ni)
#pragma unroll
        for (int reg = 0; reg < 4; ++reg) {
            const int row = t0 + quad * 4 + reg;
            const int col = wave * 64 + ni * 16 + l15;
            sfull[(size_t)row * 256 + col] = acc[ni][reg];
        }
}

// ---------------------------------------------------------------------------
// Kernel 3: bf16 MFMA GEMM, BK=64, XOR-swizzled LDS + fused LoRA epilogue.
// Round-2 structure (fastest measured): glds -> barrier -> frags+MFMA -> barrier.
// 128x128 tile, 4 waves in 2x2, each wave 64x64 (4x4 MFMA tiles), 32 MFMA
// per barrier pair.
// ---------------------------------------------------------------------------
__global__ __launch_bounds__(256) void gemm_lora(const short* __restrict__ xb,
                                                 const short* __restrict__ wb,
                                                 const float* __restrict__ base_bias,
                                                 const float* __restrict__ lora_b,
                                                 const float* __restrict__ bias_st,
                                                 const int* __restrict__ tli,
                                                 const float* __restrict__ sfull,
                                                 float* __restrict__ out) {
    __shared__ short As[BM * BK];   // 16 KB
    __shared__ short Bs[BN * BK];   // 16 KB

    const int tid = threadIdx.x;
    const int lane = tid & 63;
    const int quad = lane >> 4;
    const int l15 = lane & 15;
    const int wave = tid >> 6;
    const int wm = wave >> 1;       // wave row (0..1)
    const int wn = wave & 1;        // wave col (0..1)

    const int bn = blockIdx.x & 31;
    const int bm = blockIdx.x >> 5;
    const int t0 = bm * BM;
    const int o0 = bn * BN;

    const int lr = lane >> 3;
    const int lc = (lane & 7) ^ lr;
    const short* agl = xb + (size_t)(t0 + wave * 8 + lr) * D_ + lc * 8;
    const short* bgl = wb + (size_t)(o0 + wave * 8 + lr) * D_ + lc * 8;
    short* asl = &As[wave * 512];
    short* bsl = &Bs[wave * 512];

    f32x4 acc[4][4];
#pragma unroll
    for (int mi = 0; mi < 4; ++mi)
#pragma unroll
        for (int ni = 0; ni < 4; ++ni)
            acc[mi][ni] = f32x4{0.f, 0.f, 0.f, 0.f};

    const int arow = wm * 64 + l15;
    const int brow = wn * 64 + l15;
    const int swz = l15 & 7;

    for (int k0 = 0; k0 < D_; k0 += BK) {
#pragma unroll
        for (int j = 0; j < 4; ++j) {
            load_lds16(agl + (size_t)j * 32 * D_ + k0, asl + j * 2048);
            load_lds16(bgl + (size_t)j * 32 * D_ + k0, bsl + j * 2048);
        }
        __syncthreads();   // drains vmcnt -> tiles visible

#pragma unroll
        for (int kk = 0; kk < 2; ++kk) {
            const int cba = ((kk * 4 + quad) ^ swz) * 8;
            bf16x8 af[4], bfr[4];
#pragma unroll
            for (int i = 0; i < 4; ++i) {
                af[i]  = *(const bf16x8*)&As[(arow + i * 16) * BK + cba];
                bfr[i] = *(const bf16x8*)&Bs[(brow + i * 16) * BK + cba];
            }
#pragma unroll
            for (int mi = 0; mi < 4; ++mi)
#pragma unroll
                for (int ni = 0; ni < 4; ++ni)
                    acc[mi][ni] = __builtin_amdgcn_mfma_f32_16x16x32_bf16(
                        af[mi], bfr[ni], acc[mi][ni], 0, 0, 0);
        }
        __syncthreads();   // all waves done reading before next overwrite
    }

    // Epilogue: C/D layout col = lane&15, row = quad*4 + reg
    const int col_base = o0 + wn * 64 + l15;
#pragma unroll
    for (int mi = 0; mi < 4; ++mi) {
#pragma unroll
        for (int reg = 0; reg < 4; ++reg) {
            const int row = t0 + wm * 64 + mi * 16 + quad * 4 + reg;
            const int idx = tli[row];
            const bool valid = (idx >= 0);
            float4 s0 = {0.f, 0.f, 0.f, 0.f}, s1 = {0.f, 0.f, 0.f, 0.f};
            if (valid) {
                s0 = *(const float4*)&sfull[(size_t)row * 256 + idx * 8];
                s1 = *(const float4*)&sfull[(size_t)row * 256 + idx * 8 + 4];
            }
#pragma unroll
            for (int ni = 0; ni < 4; ++ni) {
                const int col = col_base + ni * 16;
                float r = acc[mi][ni][reg] + base_bias[col];
                if (valid) {
                    const float* bp = &lora_b[((size_t)idx * O_ + col) * R_];
                    float4 b0 = *(const float4*)&bp[0];
                    float4 b1 = *(const float4*)&bp[4];
                    r += bias_st[(size_t)idx * O_ + col];
                    r += s0.x * b0.x + s0.y * b0.y + s0.z * b0.z + s0.w * b0.w +
                         s1.x * b1.x + s1.y * b1.y + s1.z * b1.z + s1.w * b1.w;
                }
                out[(size_t)row * O_ + col] = r;
            }
        }
    }
}

// ---------------------------------------------------------------------------
extern "C" void kernel_launch(void* const* d_in, const int* in_sizes, int n_in,
                              void* d_out, int out_size, void* d_ws, size_t ws_size,
                              hipStream_t stream) {
    const float* x    = (const float*)d_in[0];   // [T,D]
    const float* w    = (const float*)d_in[1];   // [O,D]
    const float* bb   = (const float*)d_in[2];   // [O]
    const float* la   = (const float*)d_in[3];   // [L,1,R,D] == A_all [256,D]
    const float* lb   = (const float*)d_in[4];   // [L,1,O,R]
    const float* bs   = (const float*)d_in[5];   // [L,1,O]
    const int*   tli  = (const int*)d_in[6];     // [T]
    float* out = (float*)d_out;

    // ws: xb (T*D bf16) | wb (O*D bf16) | ab (256*D bf16) | sfull (T*256 f32)
    unsigned short* xb = (unsigned short*)d_ws;
    unsigned short* wb = xb + (size_t)T_ * D_;
    unsigned short* ab = wb + (size_t)O_ * D_;
    float* sfull = (float*)(ab + (size_t)256 * D_);

    cvt_kernel<<<(T_ * (size_t)D_) / 1024, 256, 0, stream>>>(x, xb);
    cvt_kernel<<<(256 * (size_t)D_) / 1024, 256, 0, stream>>>(la, ab);
    shrink_gemm<<<T_ / 16, 256, 0, stream>>>((const short*)xb, (const short*)ab, sfull);
    cvt_kernel<<<(O_ * (size_t)D_) / 1024, 256, 0, stream>>>(w, wb);
    gemm_lora<<<(T_ / BM) * (O_ / BN), 256, 0, stream>>>(
        (const short*)xb, (const short*)wb, bb, lb, bs, tli, sfull, out);
}

// Round 5
// 387.653 us; speedup vs baseline: 1.2198x; 1.0475x over previous
//
#include <hip/hip_runtime.h>

// Problem constants (fixed by the reference setup_inputs)
#define T_ 4096
#define D_ 4096
#define O_ 4096
#define L_ 32
#define R_ 8

constexpr int BM = 128, BN = 128, BK = 64;

typedef __bf16 bf16x8 __attribute__((ext_vector_type(8)));
typedef float f32x4 __attribute__((ext_vector_type(4)));

// fp32 -> bf16 round-to-nearest-even
__device__ __forceinline__ unsigned short f2bf(float f) {
    unsigned int u = __float_as_uint(f);
    u = (u + 0x7fffu + ((u >> 16) & 1u)) >> 16;
    return (unsigned short)u;
}

// async global->LDS, 16B per lane. LDS dest = wave-uniform base + lane*16.
__device__ __forceinline__ void load_lds16(const void* g, void* l) {
    __builtin_amdgcn_global_load_lds((__attribute__((address_space(1))) void*)g,
                                     (__attribute__((address_space(3))) void*)l,
                                     16, 0, 0);
}

// ---------------------------------------------------------------------------
// Kernel 1: fp32 -> bf16 streaming conversion (one float4 / thread) — used
// only for A_all (lora_a), which the merged kernel's shrink role consumes.
// ---------------------------------------------------------------------------
__global__ __launch_bounds__(256) void cvt_kernel(const float* __restrict__ src,
                                                  unsigned short* __restrict__ dst) {
    const int i = (blockIdx.x * 256 + threadIdx.x) * 4;
    float4 v = *(const float4*)&src[i];
    ushort4 o;
    o.x = f2bf(v.x); o.y = f2bf(v.y); o.z = f2bf(v.z); o.w = f2bf(v.w);
    *(ushort4*)&dst[i] = o;
}

// ---------------------------------------------------------------------------
// Kernel 2 (merged): one dispatch, three block-uniform roles:
//   blocks [0,256):        shrink  sfull = x @ A_all^T  (16x256 tile/block)
//   blocks [256,4352):     cvt_x   xb = bf16(x)   (16 elems/thread)
//   blocks [4352,8448):    cvt_w   wb = bf16(w)   (16 elems/thread)
// Shrink reads x in fp32 (inline cvt + ds_write) so it has NO dependency on
// cvt_x; the streaming cvt blocks co-reside on each CU and hide shrink's
// barrier/latency stalls.
// ---------------------------------------------------------------------------
__global__ __launch_bounds__(256) void merged_prep(const float* __restrict__ x,
                                                   const float* __restrict__ w,
                                                   const short* __restrict__ ab,
                                                   unsigned short* __restrict__ xb,
                                                   unsigned short* __restrict__ wb,
                                                   float* __restrict__ sfull) {
    __shared__ short As[16 * BK];    // 2 KB
    __shared__ short Bs[256 * BK];   // 32 KB

    const int tid = threadIdx.x;

    if (blockIdx.x >= 256) {
        // ---- streaming conversion roles ----
        const int b = blockIdx.x - 256;
        const float* src;
        unsigned short* dst;
        int bb;
        if (b < 4096) { src = x; dst = xb; bb = b; }
        else          { src = w; dst = wb; bb = b - 4096; }
        const size_t base = (size_t)bb * 4096 + tid * 4;
#pragma unroll
        for (int j = 0; j < 4; ++j) {
            float4 v = *(const float4*)&src[base + j * 1024];
            ushort4 o;
            o.x = f2bf(v.x); o.y = f2bf(v.y); o.z = f2bf(v.z); o.w = f2bf(v.w);
            *(ushort4*)&dst[base + j * 1024] = o;
        }
        return;
    }

    // ---- shrink role: tile 16 tokens x 256 lora-rows, full K ----
    const int lane = tid & 63;
    const int quad = lane >> 4;
    const int l15 = lane & 15;
    const int wave = tid >> 6;
    const int t0 = blockIdx.x * 16;

    // A staging (x fp32 -> bf16 via ds_write): thread t -> row t>>4, k-chunk (t&15)*4
    const int ar = tid >> 4;              // 0..15
    const int ak = (tid & 15) * 4;        // 0..60
    const int acb = ak >> 3;              // 16B chunk 0..7
    const int ahalf = (ak >> 2) & 1;
    short* a_dst = &As[ar * 64 + ((acb ^ (ar & 7)) * 8) + ahalf * 4];
    const float* a_src = x + (size_t)(t0 + ar) * D_ + ak;

    // B staging via glds (bf16 A_all), XOR-swizzled as in gemm_lora
    const int lr = lane >> 3;
    const int lc = (lane & 7) ^ lr;
    const short* bgl = ab + (size_t)(wave * 64 + lr) * D_ + lc * 8;
    short* bsl = &Bs[wave * 4096];        // + j*512 shorts per issue

    f32x4 acc[4];
#pragma unroll
    for (int ni = 0; ni < 4; ++ni) acc[ni] = f32x4{0.f, 0.f, 0.f, 0.f};

    const int swz = l15 & 7;

    for (int k0 = 0; k0 < D_; k0 += BK) {
        float4 av = *(const float4*)&a_src[k0];
        ushort4 ao;
        ao.x = f2bf(av.x); ao.y = f2bf(av.y); ao.z = f2bf(av.z); ao.w = f2bf(av.w);
        *(ushort4*)a_dst = ao;
#pragma unroll
        for (int j = 0; j < 8; ++j)
            load_lds16(bgl + (size_t)j * 8 * D_ + k0, bsl + j * 512);
        __syncthreads();   // drains lgkm (ds_write) + vm (glds)

#pragma unroll
        for (int kk = 0; kk < 2; ++kk) {
            const int cba = ((kk * 4 + quad) ^ swz) * 8;
            bf16x8 af = *(const bf16x8*)&As[l15 * BK + cba];
            bf16x8 bfr[4];
#pragma unroll
            for (int i = 0; i < 4; ++i)
                bfr[i] = *(const bf16x8*)&Bs[(wave * 64 + i * 16 + l15) * BK + cba];
#pragma unroll
            for (int ni = 0; ni < 4; ++ni)
                acc[ni] = __builtin_amdgcn_mfma_f32_16x16x32_bf16(
                    af, bfr[ni], acc[ni], 0, 0, 0);
        }
        __syncthreads();
    }

    // C/D layout: col = lane&15, row = quad*4 + reg
#pragma unroll
    for (int ni = 0; ni < 4; ++ni)
#pragma unroll
        for (int reg = 0; reg < 4; ++reg) {
            const int row = t0 + quad * 4 + reg;
            const int col = wave * 64 + ni * 16 + l15;
            sfull[(size_t)row * 256 + col] = acc[ni][reg];
        }
}

// ---------------------------------------------------------------------------
// Kernel 3: bf16 MFMA GEMM, BK=64, XOR-swizzled LDS + fused LoRA epilogue.
// Round-2 structure (fastest measured): glds -> barrier -> frags+MFMA -> barrier.
// ---------------------------------------------------------------------------
__global__ __launch_bounds__(256) void gemm_lora(const short* __restrict__ xb,
                                                 const short* __restrict__ wb,
                                                 const float* __restrict__ base_bias,
                                                 const float* __restrict__ lora_b,
                                                 const float* __restrict__ bias_st,
                                                 const int* __restrict__ tli,
                                                 const float* __restrict__ sfull,
                                                 float* __restrict__ out) {
    __shared__ short As[BM * BK];   // 16 KB
    __shared__ short Bs[BN * BK];   // 16 KB

    const int tid = threadIdx.x;
    const int lane = tid & 63;
    const int quad = lane >> 4;
    const int l15 = lane & 15;
    const int wave = tid >> 6;
    const int wm = wave >> 1;       // wave row (0..1)
    const int wn = wave & 1;        // wave col (0..1)

    const int bn = blockIdx.x & 31;
    const int bm = blockIdx.x >> 5;
    const int t0 = bm * BM;
    const int o0 = bn * BN;

    const int lr = lane >> 3;
    const int lc = (lane & 7) ^ lr;
    const short* agl = xb + (size_t)(t0 + wave * 8 + lr) * D_ + lc * 8;
    const short* bgl = wb + (size_t)(o0 + wave * 8 + lr) * D_ + lc * 8;
    short* asl = &As[wave * 512];
    short* bsl = &Bs[wave * 512];

    f32x4 acc[4][4];
#pragma unroll
    for (int mi = 0; mi < 4; ++mi)
#pragma unroll
        for (int ni = 0; ni < 4; ++ni)
            acc[mi][ni] = f32x4{0.f, 0.f, 0.f, 0.f};

    const int arow = wm * 64 + l15;
    const int brow = wn * 64 + l15;
    const int swz = l15 & 7;

    for (int k0 = 0; k0 < D_; k0 += BK) {
#pragma unroll
        for (int j = 0; j < 4; ++j) {
            load_lds16(agl + (size_t)j * 32 * D_ + k0, asl + j * 2048);
            load_lds16(bgl + (size_t)j * 32 * D_ + k0, bsl + j * 2048);
        }
        __syncthreads();   // drains vmcnt -> tiles visible

#pragma unroll
        for (int kk = 0; kk < 2; ++kk) {
            const int cba = ((kk * 4 + quad) ^ swz) * 8;
            bf16x8 af[4], bfr[4];
#pragma unroll
            for (int i = 0; i < 4; ++i) {
                af[i]  = *(const bf16x8*)&As[(arow + i * 16) * BK + cba];
                bfr[i] = *(const bf16x8*)&Bs[(brow + i * 16) * BK + cba];
            }
#pragma unroll
            for (int mi = 0; mi < 4; ++mi)
#pragma unroll
                for (int ni = 0; ni < 4; ++ni)
                    acc[mi][ni] = __builtin_amdgcn_mfma_f32_16x16x32_bf16(
                        af[mi], bfr[ni], acc[mi][ni], 0, 0, 0);
        }
        __syncthreads();   // all waves done reading before next overwrite
    }

    // Epilogue: C/D layout col = lane&15, row = quad*4 + reg
    const int col_base = o0 + wn * 64 + l15;
#pragma unroll
    for (int mi = 0; mi < 4; ++mi) {
#pragma unroll
        for (int reg = 0; reg < 4; ++reg) {
            const int row = t0 + wm * 64 + mi * 16 + quad * 4 + reg;
            const int idx = tli[row];
            const bool valid = (idx >= 0);
            float4 s0 = {0.f, 0.f, 0.f, 0.f}, s1 = {0.f, 0.f, 0.f, 0.f};
            if (valid) {
                s0 = *(const float4*)&sfull[(size_t)row * 256 + idx * 8];
                s1 = *(const float4*)&sfull[(size_t)row * 256 + idx * 8 + 4];
            }
#pragma unroll
            for (int ni = 0; ni < 4; ++ni) {
                const int col = col_base + ni * 16;
                float r = acc[mi][ni][reg] + base_bias[col];
                if (valid) {
                    const float* bp = &lora_b[((size_t)idx * O_ + col) * R_];
                    float4 b0 = *(const float4*)&bp[0];
                    float4 b1 = *(const float4*)&bp[4];
                    r += bias_st[(size_t)idx * O_ + col];
                    r += s0.x * b0.x + s0.y * b0.y + s0.z * b0.z + s0.w * b0.w +
                         s1.x * b1.x + s1.y * b1.y + s1.z * b1.z + s1.w * b1.w;
                }
                out[(size_t)row * O_ + col] = r;
            }
        }
    }
}

// ---------------------------------------------------------------------------
extern "C" void kernel_launch(void* const* d_in, const int* in_sizes, int n_in,
                              void* d_out, int out_size, void* d_ws, size_t ws_size,
                              hipStream_t stream) {
    const float* x    = (const float*)d_in[0];   // [T,D]
    const float* w    = (const float*)d_in[1];   // [O,D]
    const float* bb   = (const float*)d_in[2];   // [O]
    const float* la   = (const float*)d_in[3];   // [L,1,R,D] == A_all [256,D]
    const float* lb   = (const float*)d_in[4];   // [L,1,O,R]
    const float* bs   = (const float*)d_in[5];   // [L,1,O]
    const int*   tli  = (const int*)d_in[6];     // [T]
    float* out = (float*)d_out;

    // ws: xb (T*D bf16) | wb (O*D bf16) | ab (256*D bf16) | sfull (T*256 f32)
    unsigned short* xb = (unsigned short*)d_ws;
    unsigned short* wb = xb + (size_t)T_ * D_;
    unsigned short* ab = wb + (size_t)O_ * D_;
    float* sfull = (float*)(ab + (size_t)256 * D_);

    cvt_kernel<<<(256 * (size_t)D_) / 1024, 256, 0, stream>>>(la, ab);
    merged_prep<<<256 + 4096 + 4096, 256, 0, stream>>>(x, w, (const short*)ab,
                                                       xb, wb, sfull);
    gemm_lora<<<(T_ / BM) * (O_ / BN), 256, 0, stream>>>(
        (const short*)xb, (const short*)wb, bb, lb, bs, tli, sfull, out);
}